// Round 1
// baseline (68.861 us; speedup 1.0000x reference)
//
#include <hip/hip_runtime.h>

#define PI_F 3.14159265358979323846f

__device__ __forceinline__ float2 cmul(float2 a, float2 b) {
    return make_float2(fmaf(a.x, b.x, -a.y * b.y), fmaf(a.x, b.y, a.y * b.x));
}
__device__ __forceinline__ float2 cadd(float2 a, float2 b) {
    return make_float2(a.x + b.x, a.y + b.y);
}
__device__ __forceinline__ void mm2(const float2 A[2][2], const float2 B[2][2], float2 C[2][2]) {
    #pragma unroll
    for (int i = 0; i < 2; ++i)
        #pragma unroll
        for (int j = 0; j < 2; ++j)
            C[i][j] = cadd(cmul(A[i][0], B[0][j]), cmul(A[i][1], B[1][j]));
}

// One thread = one 4-qubit circuit (16 complex amps in registers).
// Qubit q occupies bit (3-q) of the flat state index (qubit 0 has stride 8).
__global__ __launch_bounds__(256) void qcnn_kernel(const float* __restrict__ x,
                                                   const float* __restrict__ w,
                                                   float* __restrict__ out,
                                                   int N) {
    // Fused per-(layer,qubit) weight gate U = RZ(w2)*RY(w1)*RX(w0), computed
    // once per block by lanes 0..7, broadcast via LDS (uniform address -> no conflict).
    __shared__ float2 Ush[2][4][4];  // [layer][qubit][U00,U01,U10,U11]
    const int t = threadIdx.x;
    if (t < 8) {
        const int h = t >> 2, q = t & 3;
        const float a = 0.5f * w[(h * 4 + q) * 3 + 0];
        const float b = 0.5f * w[(h * 4 + q) * 3 + 1];
        const float c = 0.5f * w[(h * 4 + q) * 3 + 2];
        const float ca = __cosf(a), sa = __sinf(a);
        const float cb = __cosf(b), sb = __sinf(b);
        const float cc = __cosf(c), sc = __sinf(c);
        float2 RX[2][2] = {{{ca, 0.f}, {0.f, -sa}}, {{0.f, -sa}, {ca, 0.f}}};
        float2 RY[2][2] = {{{cb, 0.f}, {-sb, 0.f}}, {{sb, 0.f}, {cb, 0.f}}};
        float2 RZ[2][2] = {{{cc, -sc}, {0.f, 0.f}}, {{0.f, 0.f}, {cc, sc}}};
        float2 T[2][2], U[2][2];
        mm2(RY, RX, T);
        mm2(RZ, T, U);
        Ush[h][q][0] = U[0][0];
        Ush[h][q][1] = U[0][1];
        Ush[h][q][2] = U[1][0];
        Ush[h][q][3] = U[1][1];
    }
    __syncthreads();

    const int n = blockIdx.x * blockDim.x + threadIdx.x;
    if (n >= N) return;

    // 12 contiguous floats per circuit; 48B stride is 16B-aligned -> 3x float4.
    const float4* xv = (const float4*)(x + (size_t)n * 12);
    const float4 xa = xv[0], xb = xv[1], xc = xv[2];
    // x[...,0] (first RZ on |0>) is a global phase -> unused.
    const float xy[4] = {xa.y, xb.x, xb.w, xc.z};  // x[q*3+1]
    const float xz[4] = {xa.z, xb.y, xc.x, xc.w};  // x[q*3+2]

    // Angle encoding as product state: v_q = (cy*e^{-i tz}, sy*e^{+i tz}).
    float2 v[4][2];
    #pragma unroll
    for (int q = 0; q < 4; ++q) {
        const float ty = 0.5f * PI_F * xy[q];
        const float tz = 0.5f * PI_F * xz[q];
        const float cy = __cosf(ty), sy = __sinf(ty);
        const float cz = __cosf(tz), sz = __sinf(tz);
        v[q][0] = make_float2(cy * cz, -cy * sz);
        v[q][1] = make_float2(sy * cz, sy * sz);
    }

    // psi = v0 (x) v1 (x) v2 (x) v3  (24 complex mults)
    float2 t01[4], t23[4], psi[16];
    #pragma unroll
    for (int i = 0; i < 2; ++i)
        #pragma unroll
        for (int j = 0; j < 2; ++j) {
            t01[i * 2 + j] = cmul(v[0][i], v[1][j]);
            t23[i * 2 + j] = cmul(v[2][i], v[3][j]);
        }
    #pragma unroll
    for (int i = 0; i < 4; ++i)
        #pragma unroll
        for (int j = 0; j < 4; ++j)
            psi[i * 4 + j] = cmul(t01[i], t23[j]);

    // Combined CZ(0,1)*CZ(2,3)*CZ(1,2) sign mask:
    // parity of (b0&b1)+(b2&b3)+(b1&b2) with b0 = bit3 ... b3 = bit0.
    const unsigned czmask = (1u << 3) | (1u << 6) | (1u << 11) |
                            (1u << 12) | (1u << 13) | (1u << 15);

    #pragma unroll
    for (int h = 0; h < 2; ++h) {
        #pragma unroll
        for (int q = 0; q < 4; ++q) {
            const float2 U00 = Ush[h][q][0], U01 = Ush[h][q][1];
            const float2 U10 = Ush[h][q][2], U11 = Ush[h][q][3];
            const int stride = 8 >> q;
            #pragma unroll
            for (int k = 0; k < 8; ++k) {
                const int lo = k & (stride - 1);
                const int i0 = ((k - lo) << 1) | lo;
                const int i1 = i0 | stride;
                const float2 p0 = psi[i0], p1 = psi[i1];
                psi[i0] = cadd(cmul(U00, p0), cmul(U01, p1));
                psi[i1] = cadd(cmul(U10, p0), cmul(U11, p1));
            }
        }
        #pragma unroll
        for (int idx = 0; idx < 16; ++idx)
            if ((czmask >> idx) & 1) {
                psi[idx].x = -psi[idx].x;
                psi[idx].y = -psi[idx].y;
            }
    }

    // PauliZ expectations: z_q = sum_idx |psi|^2 * (bit_q ? -1 : +1)
    float z[4] = {0.f, 0.f, 0.f, 0.f};
    #pragma unroll
    for (int idx = 0; idx < 16; ++idx) {
        const float p = fmaf(psi[idx].x, psi[idx].x, psi[idx].y * psi[idx].y);
        #pragma unroll
        for (int q = 0; q < 4; ++q)
            z[q] += ((idx >> (3 - q)) & 1) ? -p : p;
    }
    ((float4*)out)[n] = make_float4(z[0], z[1], z[2], z[3]);
}

extern "C" void kernel_launch(void* const* d_in, const int* in_sizes, int n_in,
                              void* d_out, int out_size, void* d_ws, size_t ws_size,
                              hipStream_t stream) {
    const float* x = (const float*)d_in[0];
    const float* w = (const float*)d_in[1];
    float* out = (float*)d_out;
    const int N = in_sizes[0] / 12;  // 128*2048 circuits, 12 floats each
    const int block = 256;
    const int grid = (N + block - 1) / block;
    qcnn_kernel<<<grid, block, 0, stream>>>(x, w, out, N);
}

// Round 2
// 63.681 us; speedup vs baseline: 1.0813x; 1.0813x over previous
//
#include <hip/hip_runtime.h>
#include <math.h>

#define PI_F 3.14159265358979323846f

// Heisenberg-picture reduction:
//   <Z_q> = gamma_q*m'z_q + (alpha_q*m'x_q + beta_q*m'y_q) * prod_{n in N(q)} m'z_n
// where m_q = (sin(th)cos(ph), sin(th)sin(ph), cos(th)), th=pi*x1, ph=pi*x2
// (the first RZ(pi*x0) is a global phase), m'_q = M1_q * m_q with M1_q the
// Bloch rotation of layer-1's RZ(c)RY(b)RX(a), and (alpha,beta,gamma)_q =
// row 3 of layer-2's Bloch rotation (layer-2 RZ drops out). CZ neighbors:
// N(0)={1}, N(1)={0,2}, N(2)={1,3}, N(3)={2}  (Z commutes with CZ).
//
// ws layout: per qubit q, 12 floats: [0..8]=M1_q row-major, [9..11]=(a,b,g)_q.

__global__ void qcnn_precompute(const float* __restrict__ w, float* __restrict__ ws) {
    const int q = threadIdx.x;
    if (q >= 4) return;
    // layer 1 -> full Bloch matrix
    {
        const float a = w[q * 3 + 0], b = w[q * 3 + 1], c = w[q * 3 + 2];
        float sa, ca, sb, cb, sc, cc;
        sincosf(a, &sa, &ca);
        sincosf(b, &sb, &cb);
        sincosf(c, &sc, &cc);
        float* o = ws + q * 12;
        o[0] = cc * cb;
        o[1] = cc * sb * sa - sc * ca;
        o[2] = cc * sb * ca + sc * sa;
        o[3] = sc * cb;
        o[4] = sc * sb * sa + cc * ca;
        o[5] = sc * sb * ca - cc * sa;
        o[6] = -sb;
        o[7] = cb * sa;
        o[8] = cb * ca;
    }
    // layer 2 -> row 3 only (RZ irrelevant before Z measurement)
    {
        const float a = w[12 + q * 3 + 0], b = w[12 + q * 3 + 1];
        float sa, ca, sb, cb;
        sincosf(a, &sa, &ca);
        sincosf(b, &sb, &cb);
        float* o = ws + q * 12;
        o[9] = -sb;
        o[10] = cb * sa;
        o[11] = cb * ca;
    }
}

__global__ __launch_bounds__(256) void qcnn_kernel(const float* __restrict__ x,
                                                   const float* __restrict__ cw,
                                                   float* __restrict__ out,
                                                   int N) {
    const int n = blockIdx.x * blockDim.x + threadIdx.x;
    if (n >= N) return;

    // 12 contiguous floats per circuit; 48B stride, 16B aligned -> 3x float4.
    const float4* xv = (const float4*)(x + (size_t)n * 12);
    const float4 xa = xv[0], xb = xv[1], xc = xv[2];
    const float xy[4] = {xa.y, xb.x, xb.w, xc.z};  // x[q*3+1] -> theta/pi
    const float xz[4] = {xa.z, xb.y, xc.x, xc.w};  // x[q*3+2] -> phi/pi

    // Per-qubit Bloch vectors of the encoded product state, rotated by the
    // layer-1 gate (cw is uniform -> s_load into SGPRs).
    float px[4], py[4], pz[4];
    #pragma unroll
    for (int q = 0; q < 4; ++q) {
        float st, ct, sp, cp;
        __sincosf(PI_F * xy[q], &st, &ct);
        __sincosf(PI_F * xz[q], &sp, &cp);
        const float mx = st * cp, my = st * sp, mz = ct;
        const float* M = cw + q * 12;
        px[q] = fmaf(M[0], mx, fmaf(M[1], my, M[2] * mz));
        py[q] = fmaf(M[3], mx, fmaf(M[4], my, M[5] * mz));
        pz[q] = fmaf(M[6], mx, fmaf(M[7], my, M[8] * mz));
    }

    float z[4];
    #pragma unroll
    for (int q = 0; q < 4; ++q) {
        const float* M = cw + q * 12;
        const float xyterm = fmaf(M[9], px[q], M[10] * py[q]);
        float nb;  // product of m'z over CZ-neighbors
        if (q == 0) nb = pz[1];
        else if (q == 1) nb = pz[0] * pz[2];
        else if (q == 2) nb = pz[1] * pz[3];
        else nb = pz[2];
        z[q] = fmaf(M[11], pz[q], xyterm * nb);
    }

    ((float4*)out)[n] = make_float4(z[0], z[1], z[2], z[3]);
}

extern "C" void kernel_launch(void* const* d_in, const int* in_sizes, int n_in,
                              void* d_out, int out_size, void* d_ws, size_t ws_size,
                              hipStream_t stream) {
    const float* x = (const float*)d_in[0];
    const float* w = (const float*)d_in[1];
    float* out = (float*)d_out;
    float* ws = (float*)d_ws;  // 48 floats of weight-derived coefficients
    const int N = in_sizes[0] / 12;  // 128*2048 circuits

    qcnn_precompute<<<1, 64, 0, stream>>>(w, ws);

    const int block = 256;
    const int grid = (N + block - 1) / block;
    qcnn_kernel<<<grid, block, 0, stream>>>(x, ws, out, N);
}

// Round 3
// 63.207 us; speedup vs baseline: 1.0894x; 1.0075x over previous
//
#include <hip/hip_runtime.h>
#include <math.h>

#define PI_F 3.14159265358979323846f

// Heisenberg-picture reduction (one fused kernel):
//   <Z_q> = gamma_q*m'z_q + (alpha_q*m'x_q + beta_q*m'y_q) * prod_{n in N(q)} m'z_n
// where m_q = (sin(th)cos(ph), sin(th)sin(ph), cos(th)), th=pi*x1, ph=pi*x2
// (the first RZ(pi*x0) is a global phase on |0> -> unused), m'_q = M1_q*m_q
// with M1_q the Bloch rotation of layer-1's RZ(c)RY(b)RX(a), and
// (alpha,beta,gamma)_q = row 3 of layer-2's Bloch rotation (layer-2's RZ
// commutes with the Z measurement and drops out). CZ neighbors (Z commutes
// with diagonal CZ): N(0)={1}, N(1)={0,2}, N(2)={1,3}, N(3)={2}.
//
// Weight coefficients (48 floats) are computed by lanes 0..7 of every block
// and broadcast via LDS -- cheaper than a serial precompute launch in the
// graph's critical path.

__global__ __launch_bounds__(256) void qcnn_kernel(const float* __restrict__ x,
                                                   const float* __restrict__ w,
                                                   float* __restrict__ out,
                                                   int N) {
    __shared__ float cw[48];  // per qubit q: [0..8]=M1_q row-major, [9..11]=(a,b,g)_q
    const int t = threadIdx.x;
    if (t < 4) {
        // layer 1 -> full Bloch rotation matrix for qubit t
        const float a = w[t * 3 + 0], b = w[t * 3 + 1], c = w[t * 3 + 2];
        float sa, ca, sb, cb, sc, cc;
        sincosf(a, &sa, &ca);
        sincosf(b, &sb, &cb);
        sincosf(c, &sc, &cc);
        float* o = cw + t * 12;
        o[0] = cc * cb;
        o[1] = cc * sb * sa - sc * ca;
        o[2] = cc * sb * ca + sc * sa;
        o[3] = sc * cb;
        o[4] = sc * sb * sa + cc * ca;
        o[5] = sc * sb * ca - cc * sa;
        o[6] = -sb;
        o[7] = cb * sa;
        o[8] = cb * ca;
    } else if (t < 8) {
        // layer 2 -> row 3 only
        const int q = t - 4;
        const float a = w[12 + q * 3 + 0], b = w[12 + q * 3 + 1];
        float sa, ca, sb, cb;
        sincosf(a, &sa, &ca);
        sincosf(b, &sb, &cb);
        float* o = cw + q * 12;
        o[9] = -sb;
        o[10] = cb * sa;
        o[11] = cb * ca;
    }
    __syncthreads();

    const int n = blockIdx.x * blockDim.x + threadIdx.x;
    if (n >= N) return;

    // 12 contiguous floats per circuit; 48B stride, 16B aligned -> 3x float4.
    const float4* xv = (const float4*)(x + (size_t)n * 12);
    const float4 xa = xv[0], xb = xv[1], xc = xv[2];
    const float xy[4] = {xa.y, xb.x, xb.w, xc.z};  // x[q*3+1] -> theta/pi
    const float xz[4] = {xa.z, xb.y, xc.x, xc.w};  // x[q*3+2] -> phi/pi

    // Per-qubit Bloch vector of the encoded product state, rotated by layer 1.
    float px[4], py[4], pz[4];
    #pragma unroll
    for (int q = 0; q < 4; ++q) {
        float st, ct, sp, cp;
        __sincosf(PI_F * xy[q], &st, &ct);
        __sincosf(PI_F * xz[q], &sp, &cp);
        const float mx = st * cp, my = st * sp, mz = ct;
        const float* M = cw + q * 12;  // uniform LDS address -> broadcast read
        px[q] = fmaf(M[0], mx, fmaf(M[1], my, M[2] * mz));
        py[q] = fmaf(M[3], mx, fmaf(M[4], my, M[5] * mz));
        pz[q] = fmaf(M[6], mx, fmaf(M[7], my, M[8] * mz));
    }

    float z[4];
    #pragma unroll
    for (int q = 0; q < 4; ++q) {
        const float* M = cw + q * 12;
        const float xyterm = fmaf(M[9], px[q], M[10] * py[q]);
        float nb;  // product of m'z over CZ-neighbors
        if (q == 0) nb = pz[1];
        else if (q == 1) nb = pz[0] * pz[2];
        else if (q == 2) nb = pz[1] * pz[3];
        else nb = pz[2];
        z[q] = fmaf(M[11], pz[q], xyterm * nb);
    }

    ((float4*)out)[n] = make_float4(z[0], z[1], z[2], z[3]);
}

extern "C" void kernel_launch(void* const* d_in, const int* in_sizes, int n_in,
                              void* d_out, int out_size, void* d_ws, size_t ws_size,
                              hipStream_t stream) {
    const float* x = (const float*)d_in[0];
    const float* w = (const float*)d_in[1];
    float* out = (float*)d_out;
    const int N = in_sizes[0] / 12;  // 128*2048 circuits, 12 floats each
    const int block = 256;
    const int grid = (N + block - 1) / block;
    qcnn_kernel<<<grid, block, 0, stream>>>(x, w, out, N);
}